// Round 5
// baseline (988.953 us; speedup 1.0000x reference)
//
#include <hip/hip_runtime.h>
#include <stdint.h>

#define B_   4
#define S_   2048
#define E_   1024
#define MQKV (B_ * S_)

typedef __bf16 bf16x8 __attribute__((ext_vector_type(8)));
typedef float f32x4 __attribute__((ext_vector_type(4)));
typedef unsigned short u16;
typedef unsigned int u32;

__device__ __forceinline__ u16 f2bf(float x) {
  union { float f; u32 u; } c; c.f = x;
  u32 r = (c.u + 0x7FFFu + ((c.u >> 16) & 1u)) >> 16;
  return (u16)r;
}
__device__ __forceinline__ float bf2f(u16 h) {
  union { u32 u; float f; } c; c.u = ((u32)h) << 16;
  return c.f;
}

__global__ __launch_bounds__(256) void cvt_f32_bf16(const float* __restrict__ src,
                                                    u16* __restrict__ dst, int n4) {
  int i = blockIdx.x * blockDim.x + threadIdx.x;
  int st = gridDim.x * blockDim.x;
  for (; i < n4; i += st) {
    float4 f = reinterpret_cast<const float4*>(src)[i];
    ushort4 o;
    o.x = f2bf(f.x); o.y = f2bf(f.y); o.z = f2bf(f.z); o.w = f2bf(f.w);
    reinterpret_cast<ushort4*>(dst)[i] = o;
  }
}

__global__ __launch_bounds__(256) void cvt_w3(const float* __restrict__ wq,
                                              const float* __restrict__ wk,
                                              const float* __restrict__ wv,
                                              u16* __restrict__ dst) {
  const int per = E_ * E_ / 4;
  int i = blockIdx.x * blockDim.x + threadIdx.x;
  const int sel = i / per;
  const int r = i - sel * per;
  const float* src = sel == 0 ? wq : (sel == 1 ? wk : wv);
  float4 f = reinterpret_cast<const float4*>(src)[r];
  ushort4 o;
  o.x = f2bf(f.x); o.y = f2bf(f.y); o.z = f2bf(f.z); o.w = f2bf(f.w);
  reinterpret_cast<ushort4*>(dst)[i] = o;
}

#define GLOAD_LDS16(g, l)                                                      \
  __builtin_amdgcn_global_load_lds(                                            \
      (const __attribute__((address_space(1))) u32*)(g),                       \
      (__attribute__((address_space(3))) u32*)(l), 16, 0, 0)

#define SGB __builtin_amdgcn_sched_group_barrier

// ============================================================================
// 256-row-tile GEMM, 8 waves (2M x 4N), BK=32, 4-slot LDS ring, counted vmcnt,
// register prefetch of next-tile fragments ENFORCED via sched_group_barrier
// ([DS_READ xN][MFMA xM] pinned per inter-barrier region), read-side XOR
// swizzle, setprio around MFMA cluster, XCD-aware block swizzle.
// C = A(MxK) * Bt(NxK)^T, bf16 in, fp32 accum.
// EPI 0: merged QKV projection (+bias, scatter to q / k / vt)
// EPI 2: exp(v*scale) bf16 store (un-normalized softmax numerator)
// EPI 3: v * invL[row], fp32 store (final out)
// ============================================================================
template <int BN, int EPI>
__global__ __launch_bounds__(512, 2) void gemm256(
    const u16* __restrict__ A, const u16* __restrict__ Bt, void* __restrict__ Cv,
    const float* __restrict__ b0, const float* __restrict__ b1,
    const float* __restrict__ b2, int N, int K, float scale,
    long sA, long sB, long sC, int gx, int gy) {
  constexpr int BM = 256;
  constexpr int NR = BN / 64;          // 4 (BN=256) or 2 (BN=128)
  constexpr int L  = 2 + BN / 128;     // global_load_lds per K-tile
  constexpr int BSLOT = BN * 32;

  __shared__ alignas(16) u16 lds[4 * BM * 32 + 4 * BSLOT];
  u16* lA = lds;
  u16* lB = lds + 4 * BM * 32;

  const int t = threadIdx.x;
  const int wv = t >> 6;
  const int ln = t & 63;
  const int wm = wv >> 2;
  const int wn = wv & 3;

  const int nwg = gridDim.x;
  int id = blockIdx.x;
  id = (id & 7) * (nwg >> 3) + (id >> 3);
  const int pz = gx * gy;
  const int z = id / pz;
  const int r2 = id - z * pz;
  const int by = r2 / gx;
  const int bx = r2 - by * gx;
  const int bm = by * BM;
  const int bn = bx * BN;

  A += (size_t)z * sA;
  Bt += (size_t)z * sB;

  const int srow = t >> 2;
  const int g0 = (t & 3) ^ (srow & 3);
  const u16* gA0 = A + (size_t)(bm + srow) * K + g0 * 8;
  const u16* gA1 = gA0 + (size_t)128 * K;
  const u16* gB0 = Bt + (size_t)(bn + srow) * K + g0 * 8;
  const u16* gB1 = gB0 + (size_t)128 * K;

  auto STAGE = [&](int u) {
    const int s = u & 3;
    const int ko = u * 32;
    GLOAD_LDS16(gA0 + ko, lA + s * 8192 + wv * 512);
    GLOAD_LDS16(gA1 + ko, lA + s * 8192 + 4096 + wv * 512);
    GLOAD_LDS16(gB0 + ko, lB + s * BSLOT + wv * 512);
    if constexpr (BN == 256) GLOAD_LDS16(gB1 + ko, lB + s * BSLOT + 4096 + wv * 512);
  };

  const int lrow = ln & 15;
  const int g = ln >> 4;
  const int aR = wm * 128 + lrow;
  const int aOff = aR * 32 + (g ^ (aR & 3)) * 8;
  const int bR = wn * (BN / 4) + lrow;
  const int bOff = bR * 32 + (g ^ (bR & 3)) * 8;

  f32x4 acc[8][NR] = {};
  const int T = K >> 5;

  bf16x8 afA[8], afB[8], bgA[NR], bgB[NR];

#define RD_A(DST, TILE) do { const u16* _p = lA + ((TILE) & 3) * 8192 + aOff;  \
  _Pragma("unroll") for (int _i = 0; _i < 8; ++_i)                             \
    DST[_i] = *reinterpret_cast<const bf16x8*>(_p + _i * 512); } while (0)
#define RD_B(DST, TILE) do { const u16* _p = lB + ((TILE) & 3) * BSLOT + bOff; \
  _Pragma("unroll") for (int _j = 0; _j < NR; ++_j)                            \
    DST[_j] = *reinterpret_cast<const bf16x8*>(_p + _j * 512); } while (0)
#define DO_MFMA(AF, BG) do { __builtin_amdgcn_s_setprio(1);                    \
  _Pragma("unroll") for (int _i = 0; _i < 8; ++_i)                             \
  _Pragma("unroll") for (int _j = 0; _j < NR; ++_j)                            \
    acc[_i][_j] = __builtin_amdgcn_mfma_f32_16x16x32_bf16(AF[_i], BG[_j],      \
                                                          acc[_i][_j], 0, 0, 0);\
  __builtin_amdgcn_s_setprio(0); } while (0)
#define VM_GATE(COND) do {                                                     \
  if (COND) { asm volatile("s_waitcnt vmcnt(%0)" :: "n"(L) : "memory"); }      \
  else { asm volatile("s_waitcnt vmcnt(0)" ::: "memory"); }                    \
  __builtin_amdgcn_s_barrier(); asm volatile("" ::: "memory"); } while (0)

  // prologue: 3 tiles in flight; tiles 0,1 resident after vmcnt(L)
  STAGE(0); STAGE(1); STAGE(2);
  asm volatile("s_waitcnt vmcnt(%0)" :: "n"(L) : "memory");
  __builtin_amdgcn_s_barrier();
  asm volatile("" ::: "memory");

  if constexpr (NR == 2) { RD_A(afA, 0); RD_B(bgA, 0); }
  else                   { RD_B(bgA, 0); }

  for (int tt = 0; tt < T; tt += 2) {
    // ---- even: compute tile tt ----
    if (tt + 3 < T) STAGE(tt + 3);
    if constexpr (NR == 2) {
      RD_A(afB, tt + 1); RD_B(bgB, tt + 1);
      DO_MFMA(afA, bgA);
      SGB(0x100, 10, 0); SGB(0x008, 16, 0);   // pin: reads first, then MFMA
    } else {
      RD_A(afA, tt); RD_B(bgB, tt + 1);
      DO_MFMA(afA, bgA);
      SGB(0x100, 12, 0); SGB(0x008, 32, 0);
    }
    VM_GATE(tt + 3 < T);

    // ---- odd: compute tile tt+1 ----
    if (tt + 4 < T) STAGE(tt + 4);
    if constexpr (NR == 2) {
      if (tt + 2 < T) {
        RD_A(afA, tt + 2); RD_B(bgA, tt + 2);
        DO_MFMA(afB, bgB);
        SGB(0x100, 10, 0); SGB(0x008, 16, 0);
      } else {
        DO_MFMA(afB, bgB);
      }
    } else {
      RD_A(afA, tt + 1);
      if (tt + 2 < T) {
        RD_B(bgA, tt + 2);
        DO_MFMA(afA, bgB);
        SGB(0x100, 12, 0); SGB(0x008, 32, 0);
      } else {
        DO_MFMA(afA, bgB);
        SGB(0x100, 8, 0); SGB(0x008, 32, 0);
      }
    }
    VM_GATE(tt + 4 < T);
  }
#undef RD_A
#undef RD_B
#undef DO_MFMA
#undef VM_GATE

  // epilogue: C/D layout col = lane&15, row = (lane>>4)*4 + reg
  const int r0 = (ln >> 4) * 4;
  const int c0 = ln & 15;
#pragma unroll
  for (int i = 0; i < 8; ++i) {
#pragma unroll
    for (int j = 0; j < NR; ++j) {
      const int col = bn + wn * (BN / 4) + j * 16 + c0;
#pragma unroll
      for (int ii = 0; ii < 4; ++ii) {
        const int row = bm + wm * 128 + i * 16 + r0 + ii;
        float v = acc[i][j][ii];
        if constexpr (EPI == 0) {
          const int sel = col >> 10;
          const int cc = col & 1023;
          const float* bb = sel == 0 ? b0 : (sel == 1 ? b1 : b2);
          v += bb[cc];
          if (sel < 2) {
            ((u16*)Cv)[(size_t)sel * 8388608 + (size_t)row * 1024 + cc] = f2bf(v);
          } else {
            const int b = row >> 11, sdx = row & 2047;
            ((u16*)Cv)[16777216 + ((size_t)b * 1024 + cc) * 2048 + sdx] = f2bf(v);
          }
        } else if constexpr (EPI == 2) {
          ((u16*)Cv)[(size_t)z * sC + (size_t)row * N + col] = f2bf(__expf(v * scale));
        } else {
          ((float*)Cv)[(size_t)z * sC + (size_t)row * N + col] = v * b0[z * 2048 + row];
        }
      }
    }
  }
}

// invL[row] = 1 / sum(expS[row][:]) ; one wave per row
__global__ __launch_bounds__(256) void row_invsum(const u16* __restrict__ P,
                                                  float* __restrict__ invL) {
  const int row = blockIdx.x * 4 + (threadIdx.x >> 6);
  const int ln = threadIdx.x & 63;
  const u16* p = P + (size_t)row * 2048 + ln * 32;
  float s = 0.f;
#pragma unroll
  for (int q = 0; q < 4; ++q) {
    uint4 r = reinterpret_cast<const uint4*>(p)[q];
    u32 w[4] = {r.x, r.y, r.z, r.w};
#pragma unroll
    for (int k = 0; k < 4; ++k) {
      s += bf2f((u16)(w[k] & 0xffffu));
      s += bf2f((u16)(w[k] >> 16));
    }
  }
  for (int o = 1; o < 64; o <<= 1) s += __shfl_xor(s, o);
  if (ln == 0) invL[row] = 1.0f / s;
}

extern "C" void kernel_launch(void* const* d_in, const int* in_sizes, int n_in,
                              void* d_out, int out_size, void* d_ws, size_t ws_size,
                              hipStream_t stream) {
  const float* x = (const float*)d_in[0];
  const float* Wq = (const float*)d_in[1];
  const float* bq = (const float*)d_in[2];
  const float* Wk = (const float*)d_in[3];
  const float* bk = (const float*)d_in[4];
  const float* Wv = (const float*)d_in[5];
  const float* bv = (const float*)d_in[6];
  float* out = (float*)d_out;

  const size_t xE = (size_t)MQKV * E_;
  const size_t need = (xE + 3 * (size_t)E_ * E_ + 3 * xE + (size_t)B_ * S_ * S_) * 2
                      + (size_t)MQKV * 4;
  if (ws_size < need) {
    hipMemsetAsync(d_out, 0, (size_t)out_size * sizeof(float), stream);
    return;
  }
  u16* xb = (u16*)d_ws;
  u16* wqkv = xb + xE;
  u16* qb = wqkv + 3 * (size_t)E_ * E_;      // q | k | vt contiguous
  u16* Pm = qb + 3 * xE;
  float* invL = (float*)(Pm + (size_t)B_ * S_ * S_);

  // 1) fp32 -> bf16
  cvt_f32_bf16<<<2048, 256, 0, stream>>>(x, xb, MQKV * E_ / 4);
  cvt_w3<<<3 * E_ * E_ / 4 / 256, 256, 0, stream>>>(Wq, Wk, Wv, wqkv);

  // 2) merged projection, BN=256: gx = 3072/256 = 12, gy = 8192/256 = 32
  gemm256<256, 0><<<384, 512, 0, stream>>>(
      xb, wqkv, qb, bq, bk, bv, 3072, E_, 1.f, 0, 0, 0, 12, 32);

  // 3) expS = exp(q k^T / 32), batched (BN=256, 256 blocks = 1 round)
  gemm256<256, 2><<<256, 512, 0, stream>>>(
      qb, qb + 8388608, Pm, nullptr, nullptr, nullptr, S_, E_, 0.03125f,
      (long)S_ * E_, (long)S_ * E_, (long)S_ * S_, 8, 8);

  // 4) row inverse sums
  row_invsum<<<B_ * S_ / 4, 256, 0, stream>>>(Pm, invL);

  // 5) out = (expS @ V) * invL  (BN=128, 256 blocks = 1 round)
  gemm256<128, 3><<<256, 512, 0, stream>>>(
      Pm, qb + 16777216, out, invL, nullptr, nullptr, E_, S_, 1.f,
      (long)S_ * S_, (long)E_ * S_, (long)S_ * E_, 8, 8);
}

// Round 6
// 189.550 us; speedup vs baseline: 5.2174x; 5.2174x over previous
//
#include <hip/hip_runtime.h>
#include <stdint.h>

#define B_   4
#define S_   2048
#define E_   1024
#define MQKV (B_ * S_)

typedef __bf16 bf16x8 __attribute__((ext_vector_type(8)));
typedef float f32x4 __attribute__((ext_vector_type(4)));
typedef unsigned short u16;
typedef unsigned int u32;

__device__ __forceinline__ u16 f2bf(float x) {
  union { float f; u32 u; } c; c.f = x;
  u32 r = (c.u + 0x7FFFu + ((c.u >> 16) & 1u)) >> 16;
  return (u16)r;
}
__device__ __forceinline__ float bf2f(u16 h) {
  union { u32 u; float f; } c; c.u = ((u32)h) << 16;
  return c.f;
}

__global__ __launch_bounds__(256) void cvt_f32_bf16(const float* __restrict__ src,
                                                    u16* __restrict__ dst, int n4) {
  int i = blockIdx.x * blockDim.x + threadIdx.x;
  int st = gridDim.x * blockDim.x;
  for (; i < n4; i += st) {
    float4 f = reinterpret_cast<const float4*>(src)[i];
    ushort4 o;
    o.x = f2bf(f.x); o.y = f2bf(f.y); o.z = f2bf(f.z); o.w = f2bf(f.w);
    reinterpret_cast<ushort4*>(dst)[i] = o;
  }
}

__global__ __launch_bounds__(256) void cvt_w3(const float* __restrict__ wq,
                                              const float* __restrict__ wk,
                                              const float* __restrict__ wv,
                                              u16* __restrict__ dst) {
  const int per = E_ * E_ / 4;
  int i = blockIdx.x * blockDim.x + threadIdx.x;
  const int sel = i / per;
  const int r = i - sel * per;
  const float* src = sel == 0 ? wq : (sel == 1 ? wk : wv);
  float4 f = reinterpret_cast<const float4*>(src)[r];
  ushort4 o;
  o.x = f2bf(f.x); o.y = f2bf(f.y); o.z = f2bf(f.z); o.w = f2bf(f.w);
  reinterpret_cast<ushort4*>(dst)[i] = o;
}

#define GLOAD_LDS16(g, l)                                                      \
  __builtin_amdgcn_global_load_lds(                                            \
      (const __attribute__((address_space(1))) u32*)(g),                       \
      (__attribute__((address_space(3))) u32*)(l), 16, 0, 0)

// ============================================================================
// Projection GEMM — R1-verified m97 structure: 128x128 tile, 4 waves, BK=32,
// single-buffer LDS + 2 barriers per K-step, 16KB LDS -> high occupancy,
// inter-block TLP hides the barrier drain (m114 mechanism).
// C[8192 x 3072] = x[8192,1024] * Wqkv[3072,1024]^T (+bias), scatter epilogue:
//   cols 0..1023 -> q (row-major), 1024..2047 -> k, 2048..3071 -> vt[b][d][s]
// ============================================================================
__global__ __launch_bounds__(256) void proj_gemm(
    const u16* __restrict__ A, const u16* __restrict__ Bt, u16* __restrict__ C,
    const float* __restrict__ b0, const float* __restrict__ b1,
    const float* __restrict__ b2) {
  constexpr int K = E_;
  __shared__ alignas(16) u16 la[128 * 32];
  __shared__ alignas(16) u16 lb[128 * 32];

  const int t = threadIdx.x;
  const int wv = t >> 6;
  const int ln = t & 63;
  const int wm = wv >> 1, wn = wv & 1;

  const int bm = blockIdx.y * 128;
  const int bn = blockIdx.x * 128;

  const int sr = t >> 2;
  const int sc = (t & 3) * 8;

  const u16* gA0 = A + (size_t)(bm + sr) * K + sc;
  const u16* gA1 = gA0 + (size_t)64 * K;
  const u16* gB0 = Bt + (size_t)(bn + sr) * K + sc;
  const u16* gB1 = gB0 + (size_t)64 * K;

  u16* lA0 = la + wv * 512;
  u16* lA1 = la + 2048 + wv * 512;
  u16* lB0 = lb + wv * 512;
  u16* lB1 = lb + 2048 + wv * 512;

  f32x4 acc[4][4] = {};

  const int lrow = ln & 15;
  const int lk = (ln >> 4) * 8;

  for (int k0 = 0; k0 < K; k0 += 32) {
    if (k0) __syncthreads();
    GLOAD_LDS16(gA0 + k0, lA0);
    GLOAD_LDS16(gA1 + k0, lA1);
    GLOAD_LDS16(gB0 + k0, lB0);
    GLOAD_LDS16(gB1 + k0, lB1);
    __syncthreads();

    bf16x8 af[4], bg[4];
#pragma unroll
    for (int i = 0; i < 4; ++i)
      af[i] = *reinterpret_cast<const bf16x8*>(&la[(wm * 64 + i * 16 + lrow) * 32 + lk]);
#pragma unroll
    for (int j = 0; j < 4; ++j)
      bg[j] = *reinterpret_cast<const bf16x8*>(&lb[(wn * 64 + j * 16 + lrow) * 32 + lk]);
#pragma unroll
    for (int i = 0; i < 4; ++i)
#pragma unroll
      for (int j = 0; j < 4; ++j)
        acc[i][j] = __builtin_amdgcn_mfma_f32_16x16x32_bf16(af[i], bg[j], acc[i][j], 0, 0, 0);
  }

  const int r0 = (ln >> 4) * 4;
  const int c0 = ln & 15;
#pragma unroll
  for (int i = 0; i < 4; ++i) {
#pragma unroll
    for (int j = 0; j < 4; ++j) {
      const int col = bn + wn * 64 + j * 16 + c0;
      const int sel = col >> 10;            // uniform per block
      const int cc = col & 1023;
      const float* bb = sel == 0 ? b0 : (sel == 1 ? b1 : b2);
#pragma unroll
      for (int ii = 0; ii < 4; ++ii) {
        const int row = bm + wm * 64 + i * 16 + r0 + ii;
        float v = acc[i][j][ii] + bb[cc];
        if (sel < 2) {   // q or k, row-major [8192][1024]
          C[(size_t)sel * 8388608 + (size_t)row * 1024 + cc] = f2bf(v);
        } else {         // vt[b][d][s]
          const int b = row >> 11, sdx = row & 2047;
          C[16777216 + ((size_t)b * 1024 + cc) * 2048 + sdx] = f2bf(v);
        }
      }
    }
  }
}

// ============================================================================
// 256-row-tile GEMM (R4-verified), 8 waves (2M x 4N), BK=32, 4-slot LDS ring,
// counted vmcnt, read-side XOR swizzle, setprio, XCD-aware block swizzle.
// Used for the two batched square GEMMs only.
// EPI 2: exp(v*scale) bf16 store (un-normalized softmax numerator)
// EPI 3: v * invL[row], fp32 store (final out)
// ============================================================================
template <int BN, int EPI>
__global__ __launch_bounds__(512, 2) void gemm256(
    const u16* __restrict__ A, const u16* __restrict__ Bt, void* __restrict__ Cv,
    const float* __restrict__ b0, int N, int K, float scale,
    long sA, long sB, long sC, int gx, int gy) {
  constexpr int BM = 256;
  constexpr int NR = BN / 64;
  constexpr int L  = 2 + BN / 128;
  constexpr int BSLOT = BN * 32;

  __shared__ alignas(16) u16 lds[4 * BM * 32 + 4 * BSLOT];
  u16* lA = lds;
  u16* lB = lds + 4 * BM * 32;

  const int t = threadIdx.x;
  const int wv = t >> 6;
  const int ln = t & 63;
  const int wm = wv >> 2;
  const int wn = wv & 3;

  const int nwg = gridDim.x;
  int id = blockIdx.x;
  id = (id & 7) * (nwg >> 3) + (id >> 3);
  const int pz = gx * gy;
  const int z = id / pz;
  const int r2 = id - z * pz;
  const int by = r2 / gx;
  const int bx = r2 - by * gx;
  const int bm = by * BM;
  const int bn = bx * BN;

  A += (size_t)z * sA;
  Bt += (size_t)z * sB;

  const int srow = t >> 2;
  const int g0 = (t & 3) ^ (srow & 3);
  const u16* gA0 = A + (size_t)(bm + srow) * K + g0 * 8;
  const u16* gA1 = gA0 + (size_t)128 * K;
  const u16* gB0 = Bt + (size_t)(bn + srow) * K + g0 * 8;
  const u16* gB1 = gB0 + (size_t)128 * K;

  auto STAGE = [&](int u) {
    const int s = u & 3;
    const int ko = u * 32;
    GLOAD_LDS16(gA0 + ko, lA + s * 8192 + wv * 512);
    GLOAD_LDS16(gA1 + ko, lA + s * 8192 + 4096 + wv * 512);
    GLOAD_LDS16(gB0 + ko, lB + s * BSLOT + wv * 512);
    if constexpr (BN == 256) GLOAD_LDS16(gB1 + ko, lB + s * BSLOT + 4096 + wv * 512);
  };

  const int lrow = ln & 15;
  const int g = ln >> 4;
  const int aR = wm * 128 + lrow;
  const int aOff = aR * 32 + (g ^ (aR & 3)) * 8;
  const int bR = wn * (BN / 4) + lrow;
  const int bOff = bR * 32 + (g ^ (bR & 3)) * 8;

  f32x4 acc[8][NR] = {};
  const int T = K >> 5;

  bf16x8 afA[8], afB[8], bgA[NR], bgB[NR];

#define RD_A(DST, TILE) do { const u16* _p = lA + ((TILE) & 3) * 8192 + aOff;  \
  _Pragma("unroll") for (int _i = 0; _i < 8; ++_i)                             \
    DST[_i] = *reinterpret_cast<const bf16x8*>(_p + _i * 512); } while (0)
#define RD_B(DST, TILE) do { const u16* _p = lB + ((TILE) & 3) * BSLOT + bOff; \
  _Pragma("unroll") for (int _j = 0; _j < NR; ++_j)                            \
    DST[_j] = *reinterpret_cast<const bf16x8*>(_p + _j * 512); } while (0)
#define DO_MFMA(AF, BG) do { __builtin_amdgcn_s_setprio(1);                    \
  _Pragma("unroll") for (int _i = 0; _i < 8; ++_i)                             \
  _Pragma("unroll") for (int _j = 0; _j < NR; ++_j)                            \
    acc[_i][_j] = __builtin_amdgcn_mfma_f32_16x16x32_bf16(AF[_i], BG[_j],      \
                                                          acc[_i][_j], 0, 0, 0);\
  __builtin_amdgcn_s_setprio(0); } while (0)
#define VM_GATE(COND) do {                                                     \
  if (COND) { asm volatile("s_waitcnt vmcnt(%0)" :: "n"(L) : "memory"); }      \
  else { asm volatile("s_waitcnt vmcnt(0)" ::: "memory"); }                    \
  __builtin_amdgcn_s_barrier(); asm volatile("" ::: "memory"); } while (0)

  STAGE(0); STAGE(1); STAGE(2);
  asm volatile("s_waitcnt vmcnt(%0)" :: "n"(L) : "memory");
  __builtin_amdgcn_s_barrier();
  asm volatile("" ::: "memory");

  if constexpr (NR == 2) { RD_A(afA, 0); RD_B(bgA, 0); }
  else                   { RD_B(bgA, 0); }

  for (int tt = 0; tt < T; tt += 2) {
    if (tt + 3 < T) STAGE(tt + 3);
    if constexpr (NR == 2) { RD_A(afB, tt + 1); RD_B(bgB, tt + 1); DO_MFMA(afA, bgA); }
    else                   { RD_A(afA, tt); RD_B(bgB, tt + 1);     DO_MFMA(afA, bgA); }
    VM_GATE(tt + 3 < T);

    if (tt + 4 < T) STAGE(tt + 4);
    if constexpr (NR == 2) {
      if (tt + 2 < T) { RD_A(afA, tt + 2); RD_B(bgA, tt + 2); }
      DO_MFMA(afB, bgB);
    } else {
      RD_A(afA, tt + 1);
      if (tt + 2 < T) RD_B(bgA, tt + 2);
      DO_MFMA(afA, bgB);
    }
    VM_GATE(tt + 4 < T);
  }
#undef RD_A
#undef RD_B
#undef DO_MFMA
#undef VM_GATE

  const int r0 = (ln >> 4) * 4;
  const int c0 = ln & 15;
#pragma unroll
  for (int i = 0; i < 8; ++i) {
#pragma unroll
    for (int j = 0; j < NR; ++j) {
      const int col = bn + wn * (BN / 4) + j * 16 + c0;
#pragma unroll
      for (int ii = 0; ii < 4; ++ii) {
        const int row = bm + wm * 128 + i * 16 + r0 + ii;
        float v = acc[i][j][ii];
        if constexpr (EPI == 2) {
          ((u16*)Cv)[(size_t)z * sC + (size_t)row * N + col] = f2bf(__expf(v * scale));
        } else {
          ((float*)Cv)[(size_t)z * sC + (size_t)row * N + col] = v * b0[z * 2048 + row];
        }
      }
    }
  }
}

// invL[row] = 1 / sum(expS[row][:]) ; one wave per row
__global__ __launch_bounds__(256) void row_invsum(const u16* __restrict__ P,
                                                  float* __restrict__ invL) {
  const int row = blockIdx.x * 4 + (threadIdx.x >> 6);
  const int ln = threadIdx.x & 63;
  const u16* p = P + (size_t)row * 2048 + ln * 32;
  float s = 0.f;
#pragma unroll
  for (int q = 0; q < 4; ++q) {
    uint4 r = reinterpret_cast<const uint4*>(p)[q];
    u32 w[4] = {r.x, r.y, r.z, r.w};
#pragma unroll
    for (int k = 0; k < 4; ++k) {
      s += bf2f((u16)(w[k] & 0xffffu));
      s += bf2f((u16)(w[k] >> 16));
    }
  }
  for (int o = 1; o < 64; o <<= 1) s += __shfl_xor(s, o);
  if (ln == 0) invL[row] = 1.0f / s;
}

extern "C" void kernel_launch(void* const* d_in, const int* in_sizes, int n_in,
                              void* d_out, int out_size, void* d_ws, size_t ws_size,
                              hipStream_t stream) {
  const float* x = (const float*)d_in[0];
  const float* Wq = (const float*)d_in[1];
  const float* bq = (const float*)d_in[2];
  const float* Wk = (const float*)d_in[3];
  const float* bk = (const float*)d_in[4];
  const float* Wv = (const float*)d_in[5];
  const float* bv = (const float*)d_in[6];
  float* out = (float*)d_out;

  const size_t xE = (size_t)MQKV * E_;
  const size_t need = (xE + 3 * (size_t)E_ * E_ + 3 * xE + (size_t)B_ * S_ * S_) * 2
                      + (size_t)MQKV * 4;
  if (ws_size < need) {
    hipMemsetAsync(d_out, 0, (size_t)out_size * sizeof(float), stream);
    return;
  }
  u16* xb = (u16*)d_ws;
  u16* wqkv = xb + xE;
  u16* qb = wqkv + 3 * (size_t)E_ * E_;      // q | k | vt contiguous
  u16* Pm = qb + 3 * xE;
  float* invL = (float*)(Pm + (size_t)B_ * S_ * S_);

  // 1) fp32 -> bf16
  cvt_f32_bf16<<<2048, 256, 0, stream>>>(x, xb, MQKV * E_ / 4);
  cvt_w3<<<3 * E_ * E_ / 4 / 256, 256, 0, stream>>>(Wq, Wk, Wv, wqkv);

  // 2) merged projection, m97-style: grid (3072/128, 8192/128) = (24, 64)
  proj_gemm<<<dim3(24, 64), 256, 0, stream>>>(xb, wqkv, qb, bq, bk, bv);

  // 3) expS = exp(q k^T / 32), batched (BN=256, 256 blocks = 1 round)
  gemm256<256, 2><<<256, 512, 0, stream>>>(
      qb, qb + 8388608, Pm, nullptr, S_, E_, 0.03125f,
      (long)S_ * E_, (long)S_ * E_, (long)S_ * S_, 8, 8);

  // 4) row inverse sums
  row_invsum<<<B_ * S_ / 4, 256, 0, stream>>>(Pm, invL);

  // 5) out = (expS @ V) * invL  (BN=128, 256 blocks = 1 round)
  gemm256<128, 3><<<256, 512, 0, stream>>>(
      Pm, qb + 16777216, out, invL, E_, S_, 1.f,
      (long)S_ * S_, (long)E_ * S_, (long)S_ * E_, 8, 8);
}

// Round 7
// 168.345 us; speedup vs baseline: 5.8746x; 1.1260x over previous
//
#include <hip/hip_runtime.h>
#include <stdint.h>

#define B_   4
#define S_   2048
#define E_   1024
#define MQKV (B_ * S_)

typedef __bf16 bf16x8 __attribute__((ext_vector_type(8)));
typedef float f32x4 __attribute__((ext_vector_type(4)));
typedef unsigned short u16;
typedef unsigned int u32;

__device__ __forceinline__ u16 f2bf(float x) {
  union { float f; u32 u; } c; c.f = x;
  u32 r = (c.u + 0x7FFFu + ((c.u >> 16) & 1u)) >> 16;
  return (u16)r;
}
__device__ __forceinline__ float bf2f(u16 h) {
  union { u32 u; float f; } c; c.u = ((u32)h) << 16;
  return c.f;
}

__global__ __launch_bounds__(256) void cvt_f32_bf16(const float* __restrict__ src,
                                                    u16* __restrict__ dst, int n4) {
  int i = blockIdx.x * blockDim.x + threadIdx.x;
  int st = gridDim.x * blockDim.x;
  for (; i < n4; i += st) {
    float4 f = reinterpret_cast<const float4*>(src)[i];
    ushort4 o;
    o.x = f2bf(f.x); o.y = f2bf(f.y); o.z = f2bf(f.z); o.w = f2bf(f.w);
    reinterpret_cast<ushort4*>(dst)[i] = o;
  }
}

__global__ __launch_bounds__(256) void cvt_w3(const float* __restrict__ wq,
                                              const float* __restrict__ wk,
                                              const float* __restrict__ wv,
                                              u16* __restrict__ dst) {
  const int per = E_ * E_ / 4;
  int i = blockIdx.x * blockDim.x + threadIdx.x;
  const int sel = i / per;
  const int r = i - sel * per;
  const float* src = sel == 0 ? wq : (sel == 1 ? wk : wv);
  float4 f = reinterpret_cast<const float4*>(src)[r];
  ushort4 o;
  o.x = f2bf(f.x); o.y = f2bf(f.y); o.z = f2bf(f.z); o.w = f2bf(f.w);
  reinterpret_cast<ushort4*>(dst)[i] = o;
}

#define GLOAD_LDS16(g, l)                                                      \
  __builtin_amdgcn_global_load_lds(                                            \
      (const __attribute__((address_space(1))) u32*)(g),                       \
      (__attribute__((address_space(3))) u32*)(l), 16, 0, 0)

// ============================================================================
// 256-row-tile GEMM (R4/R6-verified ring), 8 waves (2M x 4N), BK=32,
// 4-slot LDS ring, counted vmcnt, read-side XOR swizzle, setprio, XCD swizzle.
// C = A(M x K, row stride ldA) * Bt(N x K, row stride ldB)^T, bf16 in, f32 acc.
// EPI 0: qk-projection: +bias (b0 for col<1024 -> q, b1 -> k), bf16 row-major
// EPI 1: v-projection-transposed: +b0[row], bf16 row-major (z-batched)
// EPI 2: exp(v*scale), bf16 (un-normalized softmax numerator)
// EPI 3: v * b0[z*2048+row] (invL), fp32 (final out)
// ============================================================================
template <int BN, int EPI>
__global__ __launch_bounds__(512, 2) void gemm256(
    const u16* __restrict__ A, const u16* __restrict__ Bt, void* __restrict__ Cv,
    const float* __restrict__ b0, const float* __restrict__ b1,
    int N, int K, float scale,
    long sA, long sB, long sC, long ldA, long ldB, int gx, int gy) {
  constexpr int BM = 256;
  constexpr int NR = BN / 64;
  constexpr int L  = 2 + BN / 128;
  constexpr int BSLOT = BN * 32;

  __shared__ alignas(16) u16 lds[4 * BM * 32 + 4 * BSLOT];
  u16* lA = lds;
  u16* lB = lds + 4 * BM * 32;

  const int t = threadIdx.x;
  const int wv = t >> 6;
  const int ln = t & 63;
  const int wm = wv >> 2;
  const int wn = wv & 3;

  const int nwg = gridDim.x;
  int id = blockIdx.x;
  id = (id & 7) * (nwg >> 3) + (id >> 3);
  const int pz = gx * gy;
  const int z = id / pz;
  const int r2 = id - z * pz;
  const int by = r2 / gx;
  const int bx = r2 - by * gx;
  const int bm = by * BM;
  const int bn = bx * BN;

  A += (size_t)z * sA;
  Bt += (size_t)z * sB;

  const int srow = t >> 2;
  const int g0 = (t & 3) ^ (srow & 3);
  const u16* gA0 = A + (size_t)(bm + srow) * ldA + g0 * 8;
  const u16* gA1 = gA0 + (size_t)128 * ldA;
  const u16* gB0 = Bt + (size_t)(bn + srow) * ldB + g0 * 8;
  const u16* gB1 = gB0 + (size_t)128 * ldB;

  auto STAGE = [&](int u) {
    const int s = u & 3;
    const int ko = u * 32;
    GLOAD_LDS16(gA0 + ko, lA + s * 8192 + wv * 512);
    GLOAD_LDS16(gA1 + ko, lA + s * 8192 + 4096 + wv * 512);
    GLOAD_LDS16(gB0 + ko, lB + s * BSLOT + wv * 512);
    if constexpr (BN == 256) GLOAD_LDS16(gB1 + ko, lB + s * BSLOT + 4096 + wv * 512);
  };

  const int lrow = ln & 15;
  const int g = ln >> 4;
  const int aR = wm * 128 + lrow;
  const int aOff = aR * 32 + (g ^ (aR & 3)) * 8;
  const int bR = wn * (BN / 4) + lrow;
  const int bOff = bR * 32 + (g ^ (bR & 3)) * 8;

  f32x4 acc[8][NR] = {};
  const int T = K >> 5;

  bf16x8 afA[8], afB[8], bgA[NR], bgB[NR];

#define RD_A(DST, TILE) do { const u16* _p = lA + ((TILE) & 3) * 8192 + aOff;  \
  _Pragma("unroll") for (int _i = 0; _i < 8; ++_i)                             \
    DST[_i] = *reinterpret_cast<const bf16x8*>(_p + _i * 512); } while (0)
#define RD_B(DST, TILE) do { const u16* _p = lB + ((TILE) & 3) * BSLOT + bOff; \
  _Pragma("unroll") for (int _j = 0; _j < NR; ++_j)                            \
    DST[_j] = *reinterpret_cast<const bf16x8*>(_p + _j * 512); } while (0)
#define DO_MFMA(AF, BG) do { __builtin_amdgcn_s_setprio(1);                    \
  _Pragma("unroll") for (int _i = 0; _i < 8; ++_i)                             \
  _Pragma("unroll") for (int _j = 0; _j < NR; ++_j)                            \
    acc[_i][_j] = __builtin_amdgcn_mfma_f32_16x16x32_bf16(AF[_i], BG[_j],      \
                                                          acc[_i][_j], 0, 0, 0);\
  __builtin_amdgcn_s_setprio(0); } while (0)
#define VM_GATE(COND) do {                                                     \
  if (COND) { asm volatile("s_waitcnt vmcnt(%0)" :: "n"(L) : "memory"); }      \
  else { asm volatile("s_waitcnt vmcnt(0)" ::: "memory"); }                    \
  __builtin_amdgcn_s_barrier(); asm volatile("" ::: "memory"); } while (0)

  STAGE(0); STAGE(1); STAGE(2);
  asm volatile("s_waitcnt vmcnt(%0)" :: "n"(L) : "memory");
  __builtin_amdgcn_s_barrier();
  asm volatile("" ::: "memory");

  if constexpr (NR == 2) { RD_A(afA, 0); RD_B(bgA, 0); }
  else                   { RD_B(bgA, 0); }

  for (int tt = 0; tt < T; tt += 2) {
    if (tt + 3 < T) STAGE(tt + 3);
    if constexpr (NR == 2) { RD_A(afB, tt + 1); RD_B(bgB, tt + 1); DO_MFMA(afA, bgA); }
    else                   { RD_A(afA, tt); RD_B(bgB, tt + 1);     DO_MFMA(afA, bgA); }
    VM_GATE(tt + 3 < T);

    if (tt + 4 < T) STAGE(tt + 4);
    if constexpr (NR == 2) {
      if (tt + 2 < T) { RD_A(afA, tt + 2); RD_B(bgA, tt + 2); }
      DO_MFMA(afB, bgB);
    } else {
      RD_A(afA, tt + 1);
      if (tt + 2 < T) RD_B(bgA, tt + 2);
      DO_MFMA(afA, bgB);
    }
    VM_GATE(tt + 4 < T);
  }
#undef RD_A
#undef RD_B
#undef DO_MFMA
#undef VM_GATE

  const int r0 = (ln >> 4) * 4;
  const int c0 = ln & 15;
#pragma unroll
  for (int i = 0; i < 8; ++i) {
#pragma unroll
    for (int j = 0; j < NR; ++j) {
      const int col = bn + wn * (BN / 4) + j * 16 + c0;
#pragma unroll
      for (int ii = 0; ii < 4; ++ii) {
        const int row = bm + wm * 128 + i * 16 + r0 + ii;
        float v = acc[i][j][ii];
        if constexpr (EPI == 0) {
          const float bb = (col < 1024) ? b0[col] : b1[col - 1024];
          ((u16*)Cv)[(size_t)row * N + col] = f2bf(v + bb);
        } else if constexpr (EPI == 1) {
          ((u16*)Cv)[(size_t)z * sC + (size_t)row * N + col] = f2bf(v + b0[row]);
        } else if constexpr (EPI == 2) {
          ((u16*)Cv)[(size_t)z * sC + (size_t)row * N + col] = f2bf(__expf(v * scale));
        } else {
          ((float*)Cv)[(size_t)z * sC + (size_t)row * N + col] = v * b0[z * 2048 + row];
        }
      }
    }
  }
}

// invL[row] = 1 / sum(expS[row][:]) ; one wave per row
__global__ __launch_bounds__(256) void row_invsum(const u16* __restrict__ P,
                                                  float* __restrict__ invL) {
  const int row = blockIdx.x * 4 + (threadIdx.x >> 6);
  const int ln = threadIdx.x & 63;
  const u16* p = P + (size_t)row * 2048 + ln * 32;
  float s = 0.f;
#pragma unroll
  for (int q = 0; q < 4; ++q) {
    uint4 r = reinterpret_cast<const uint4*>(p)[q];
    u32 w[4] = {r.x, r.y, r.z, r.w};
#pragma unroll
    for (int k = 0; k < 4; ++k) {
      s += bf2f((u16)(w[k] & 0xffffu));
      s += bf2f((u16)(w[k] >> 16));
    }
  }
  for (int o = 1; o < 64; o <<= 1) s += __shfl_xor(s, o);
  if (ln == 0) invL[row] = 1.0f / s;
}

extern "C" void kernel_launch(void* const* d_in, const int* in_sizes, int n_in,
                              void* d_out, int out_size, void* d_ws, size_t ws_size,
                              hipStream_t stream) {
  const float* x = (const float*)d_in[0];
  const float* Wq = (const float*)d_in[1];
  const float* bq = (const float*)d_in[2];
  const float* Wk = (const float*)d_in[3];
  const float* bk = (const float*)d_in[4];
  const float* Wv = (const float*)d_in[5];
  const float* bv = (const float*)d_in[6];
  float* out = (float*)d_out;

  // workspace (bf16 unless noted):
  //   xb   [8192][1024]          16 MB
  //   wqkv [3072][1024]           6 MB  (Wq | Wk | Wv rows)
  //   qk   [8192][2048]          32 MB  (cols 0..1023 = q, 1024..2047 = k)
  //   vt   [4][1024][2048]       16 MB
  //   Pm   [4][2048][2048]       32 MB
  //   invL [8192] f32            32 KB
  const size_t xE = (size_t)MQKV * E_;
  const size_t qkE = (size_t)MQKV * 2048;
  const size_t need = (xE + 3 * (size_t)E_ * E_ + qkE + xE + (size_t)B_ * S_ * S_) * 2
                      + (size_t)MQKV * 4;
  if (ws_size < need) {
    hipMemsetAsync(d_out, 0, (size_t)out_size * sizeof(float), stream);
    return;
  }
  u16* xb = (u16*)d_ws;
  u16* wqkv = xb + xE;
  u16* qk = wqkv + 3 * (size_t)E_ * E_;
  u16* vt = qk + qkE;
  u16* Pm = vt + xE;
  float* invL = (float*)(Pm + (size_t)B_ * S_ * S_);

  // 1) fp32 -> bf16
  cvt_f32_bf16<<<2048, 256, 0, stream>>>(x, xb, MQKV * E_ / 4);
  cvt_w3<<<3 * E_ * E_ / 4 / 256, 256, 0, stream>>>(Wq, Wk, Wv, wqkv);

  // 2) qk-projection: [8192,1024] x [2048,1024]^T -> qk[8192][2048]
  //    grid (2048/256) x (8192/256) = 8 x 32 = 256 blocks = 1 full round
  gemm256<256, 0><<<256, 512, 0, stream>>>(
      xb, wqkv, qk, bq, bk, 2048, E_, 1.f,
      0, 0, 0, E_, E_, 8, 32);

  // 3) v-projection, transposed: vt[b] = Wv x[b]^T  (M=1024, N=2048, z=4)
  //    grid (2048/128) x (1024/256) x 4 = 16 x 4 x 4 = 256 blocks
  gemm256<128, 1><<<256, 512, 0, stream>>>(
      wqkv + 2 * (size_t)E_ * E_, xb, vt, bv, nullptr, 2048, E_, 1.f,
      0, (long)S_ * E_, (long)E_ * S_, E_, E_, 16, 4);

  // 4) expS = exp(q k^T / 32): A = qk (q cols), Bt = qk + 1024 (k cols)
  gemm256<256, 2><<<256, 512, 0, stream>>>(
      qk, qk + 1024, Pm, nullptr, nullptr, 2048, E_, 0.03125f,
      (long)S_ * 2048, (long)S_ * 2048, (long)S_ * S_, 2048, 2048, 8, 8);

  // 5) row inverse sums
  row_invsum<<<B_ * S_ / 4, 256, 0, stream>>>(Pm, invL);

  // 6) out = (expS @ V) * invL
  gemm256<128, 3><<<256, 512, 0, stream>>>(
      Pm, vt, out, invL, nullptr, E_, S_, 1.f,
      (long)S_ * S_, (long)E_ * S_, (long)S_ * E_, 2048, 2048, 8, 8);
}

// Round 8
// 166.706 us; speedup vs baseline: 5.9323x; 1.0098x over previous
//
#include <hip/hip_runtime.h>
#include <stdint.h>

#define B_   4
#define S_   2048
#define E_   1024
#define MQKV (B_ * S_)
#define LDP  2112   // padded row stride (u16) for Pm and vt: 4224B, de-camps 4KB aliasing

typedef __bf16 bf16x8 __attribute__((ext_vector_type(8)));
typedef float f32x4 __attribute__((ext_vector_type(4)));
typedef unsigned short u16;
typedef unsigned int u32;

__device__ __forceinline__ u16 f2bf(float x) {
  union { float f; u32 u; } c; c.f = x;
  u32 r = (c.u + 0x7FFFu + ((c.u >> 16) & 1u)) >> 16;
  return (u16)r;
}
__device__ __forceinline__ float bf2f(u16 h) {
  union { u32 u; float f; } c; c.u = ((u32)h) << 16;
  return c.f;
}

__global__ __launch_bounds__(256) void cvt_f32_bf16(const float* __restrict__ src,
                                                    u16* __restrict__ dst, int n4) {
  int i = blockIdx.x * blockDim.x + threadIdx.x;
  int st = gridDim.x * blockDim.x;
  for (; i < n4; i += st) {
    float4 f = reinterpret_cast<const float4*>(src)[i];
    ushort4 o;
    o.x = f2bf(f.x); o.y = f2bf(f.y); o.z = f2bf(f.z); o.w = f2bf(f.w);
    reinterpret_cast<ushort4*>(dst)[i] = o;
  }
}

__global__ __launch_bounds__(256) void cvt_w3(const float* __restrict__ wq,
                                              const float* __restrict__ wk,
                                              const float* __restrict__ wv,
                                              u16* __restrict__ dst) {
  const int per = E_ * E_ / 4;
  int i = blockIdx.x * blockDim.x + threadIdx.x;
  const int sel = i / per;
  const int r = i - sel * per;
  const float* src = sel == 0 ? wq : (sel == 1 ? wk : wv);
  float4 f = reinterpret_cast<const float4*>(src)[r];
  ushort4 o;
  o.x = f2bf(f.x); o.y = f2bf(f.y); o.z = f2bf(f.z); o.w = f2bf(f.w);
  reinterpret_cast<ushort4*>(dst)[i] = o;
}

#define GLOAD_LDS16(g, l)                                                      \
  __builtin_amdgcn_global_load_lds(                                            \
      (const __attribute__((address_space(1))) u32*)(g),                       \
      (__attribute__((address_space(3))) u32*)(l), 16, 0, 0)

// ============================================================================
// 256-row-tile GEMM (ring), 8 waves (2M x 4N), BK=32, 4-slot LDS ring,
// counted vmcnt, read-side XOR swizzle, setprio, XCD swizzle.
// C = A(M x K, row stride ldA) * Bt(N x K, row stride ldB)^T, bf16 in, f32 acc.
// EPI 0: qk-projection: +bias, scatter col<1024 -> q, else -> k (both ld 1024)
// EPI 1: v-projection-transposed: +b0[row], bf16, ldC-strided (z-batched)
// EPI 2: exp(v*scale), bf16, ldC-strided
// EPI 3: v * b0[z*2048+row] (invL), fp32, ldC-strided (final out)
// ============================================================================
template <int BN, int EPI>
__global__ __launch_bounds__(512, 2) void gemm256(
    const u16* __restrict__ A, const u16* __restrict__ Bt, void* __restrict__ Cv,
    const float* __restrict__ b0, const float* __restrict__ b1,
    int N, int K, float scale,
    long sA, long sB, long sC, long ldA, long ldB, long ldC, int gx, int gy) {
  constexpr int BM = 256;
  constexpr int NR = BN / 64;
  constexpr int L  = 2 + BN / 128;
  constexpr int BSLOT = BN * 32;

  __shared__ alignas(16) u16 lds[4 * BM * 32 + 4 * BSLOT];
  u16* lA = lds;
  u16* lB = lds + 4 * BM * 32;

  const int t = threadIdx.x;
  const int wv = t >> 6;
  const int ln = t & 63;
  const int wm = wv >> 2;
  const int wn = wv & 3;

  const int nwg = gridDim.x;
  int id = blockIdx.x;
  id = (id & 7) * (nwg >> 3) + (id >> 3);
  const int pz = gx * gy;
  const int z = id / pz;
  const int r2 = id - z * pz;
  const int by = r2 / gx;
  const int bx = r2 - by * gx;
  const int bm = by * BM;
  const int bn = bx * BN;

  A += (size_t)z * sA;
  Bt += (size_t)z * sB;

  const int srow = t >> 2;
  const int g0 = (t & 3) ^ (srow & 3);
  const u16* gA0 = A + (size_t)(bm + srow) * ldA + g0 * 8;
  const u16* gA1 = gA0 + (size_t)128 * ldA;
  const u16* gB0 = Bt + (size_t)(bn + srow) * ldB + g0 * 8;
  const u16* gB1 = gB0 + (size_t)128 * ldB;

  auto STAGE = [&](int u) {
    const int s = u & 3;
    const int ko = u * 32;
    GLOAD_LDS16(gA0 + ko, lA + s * 8192 + wv * 512);
    GLOAD_LDS16(gA1 + ko, lA + s * 8192 + 4096 + wv * 512);
    GLOAD_LDS16(gB0 + ko, lB + s * BSLOT + wv * 512);
    if constexpr (BN == 256) GLOAD_LDS16(gB1 + ko, lB + s * BSLOT + 4096 + wv * 512);
  };

  const int lrow = ln & 15;
  const int g = ln >> 4;
  const int aR = wm * 128 + lrow;
  const int aOff = aR * 32 + (g ^ (aR & 3)) * 8;
  const int bR = wn * (BN / 4) + lrow;
  const int bOff = bR * 32 + (g ^ (bR & 3)) * 8;

  f32x4 acc[8][NR] = {};
  const int T = K >> 5;

  bf16x8 afA[8], afB[8], bgA[NR], bgB[NR];

#define RD_A(DST, TILE) do { const u16* _p = lA + ((TILE) & 3) * 8192 + aOff;  \
  _Pragma("unroll") for (int _i = 0; _i < 8; ++_i)                             \
    DST[_i] = *reinterpret_cast<const bf16x8*>(_p + _i * 512); } while (0)
#define RD_B(DST, TILE) do { const u16* _p = lB + ((TILE) & 3) * BSLOT + bOff; \
  _Pragma("unroll") for (int _j = 0; _j < NR; ++_j)                            \
    DST[_j] = *reinterpret_cast<const bf16x8*>(_p + _j * 512); } while (0)
#define DO_MFMA(AF, BG) do { __builtin_amdgcn_s_setprio(1);                    \
  _Pragma("unroll") for (int _i = 0; _i < 8; ++_i)                             \
  _Pragma("unroll") for (int _j = 0; _j < NR; ++_j)                            \
    acc[_i][_j] = __builtin_amdgcn_mfma_f32_16x16x32_bf16(AF[_i], BG[_j],      \
                                                          acc[_i][_j], 0, 0, 0);\
  __builtin_amdgcn_s_setprio(0); } while (0)
#define VM_GATE(COND) do {                                                     \
  if (COND) { asm volatile("s_waitcnt vmcnt(%0)" :: "n"(L) : "memory"); }      \
  else { asm volatile("s_waitcnt vmcnt(0)" ::: "memory"); }                    \
  __builtin_amdgcn_s_barrier(); asm volatile("" ::: "memory"); } while (0)

  STAGE(0); STAGE(1); STAGE(2);
  asm volatile("s_waitcnt vmcnt(%0)" :: "n"(L) : "memory");
  __builtin_amdgcn_s_barrier();
  asm volatile("" ::: "memory");

  if constexpr (NR == 2) { RD_A(afA, 0); RD_B(bgA, 0); }
  else                   { RD_B(bgA, 0); }

  for (int tt = 0; tt < T; tt += 2) {
    if (tt + 3 < T) STAGE(tt + 3);
    if constexpr (NR == 2) { RD_A(afB, tt + 1); RD_B(bgB, tt + 1); DO_MFMA(afA, bgA); }
    else                   { RD_A(afA, tt); RD_B(bgB, tt + 1);     DO_MFMA(afA, bgA); }
    VM_GATE(tt + 3 < T);

    if (tt + 4 < T) STAGE(tt + 4);
    if constexpr (NR == 2) {
      if (tt + 2 < T) { RD_A(afA, tt + 2); RD_B(bgA, tt + 2); }
      DO_MFMA(afB, bgB);
    } else {
      RD_A(afA, tt + 1);
      if (tt + 2 < T) RD_B(bgA, tt + 2);
      DO_MFMA(afA, bgB);
    }
    VM_GATE(tt + 4 < T);
  }
#undef RD_A
#undef RD_B
#undef DO_MFMA
#undef VM_GATE

  const int r0 = (ln >> 4) * 4;
  const int c0 = ln & 15;
#pragma unroll
  for (int i = 0; i < 8; ++i) {
#pragma unroll
    for (int j = 0; j < NR; ++j) {
      const int col = bn + wn * (BN / 4) + j * 16 + c0;
#pragma unroll
      for (int ii = 0; ii < 4; ++ii) {
        const int row = bm + wm * 128 + i * 16 + r0 + ii;
        float v = acc[i][j][ii];
        if constexpr (EPI == 0) {
          const int sel = col >> 10;          // uniform per block (256 | 1024)
          const int cc = col & 1023;
          const float bb = sel == 0 ? b0[cc] : b1[cc];
          ((u16*)Cv)[(size_t)sel * 8388608 + (size_t)row * 1024 + cc] = f2bf(v + bb);
        } else if constexpr (EPI == 1) {
          ((u16*)Cv)[(size_t)z * sC + (size_t)row * ldC + col] = f2bf(v + b0[row]);
        } else if constexpr (EPI == 2) {
          ((u16*)Cv)[(size_t)z * sC + (size_t)row * ldC + col] = f2bf(__expf(v * scale));
        } else {
          ((float*)Cv)[(size_t)z * sC + (size_t)row * ldC + col] = v * b0[z * 2048 + row];
        }
      }
    }
  }
}

// invL[row] = 1 / sum(expS[row][:2048]) ; one wave per row; Pm rows LDP-strided
__global__ __launch_bounds__(256) void row_invsum(const u16* __restrict__ P,
                                                  float* __restrict__ invL) {
  const int row = blockIdx.x * 4 + (threadIdx.x >> 6);
  const int ln = threadIdx.x & 63;
  const u16* p = P + (size_t)row * LDP + ln * 32;
  float s = 0.f;
#pragma unroll
  for (int q = 0; q < 4; ++q) {
    uint4 r = reinterpret_cast<const uint4*>(p)[q];
    u32 w[4] = {r.x, r.y, r.z, r.w};
#pragma unroll
    for (int k = 0; k < 4; ++k) {
      s += bf2f((u16)(w[k] & 0xffffu));
      s += bf2f((u16)(w[k] >> 16));
    }
  }
  for (int o = 1; o < 64; o <<= 1) s += __shfl_xor(s, o);
  if (ln == 0) invL[row] = 1.0f / s;
}

extern "C" void kernel_launch(void* const* d_in, const int* in_sizes, int n_in,
                              void* d_out, int out_size, void* d_ws, size_t ws_size,
                              hipStream_t stream) {
  const float* x = (const float*)d_in[0];
  const float* Wq = (const float*)d_in[1];
  const float* bq = (const float*)d_in[2];
  const float* Wk = (const float*)d_in[3];
  const float* bk = (const float*)d_in[4];
  const float* Wv = (const float*)d_in[5];
  const float* bv = (const float*)d_in[6];
  float* out = (float*)d_out;

  // workspace (u16 elements):
  //   xb   [8192][1024]            8388608
  //   wqkv [3072][1024]            3145728
  //   q    [8192][1024]            8388608   (k = q + 8388608, contiguous)
  //   k    [8192][1024]            8388608
  //   vt   [4][1024][LDP]          8650752
  //   Pm   [4][2048][LDP]         17301504
  //   invL [8192] f32
  const size_t xE = 8388608, wE = 3145728, qE = 8388608;
  const size_t vtE = (size_t)4 * 1024 * LDP;
  const size_t PmE = (size_t)4 * 2048 * LDP;
  const size_t need = (xE + wE + 2 * qE + vtE + PmE) * 2 + (size_t)MQKV * 4;
  if (ws_size < need) {
    hipMemsetAsync(d_out, 0, (size_t)out_size * sizeof(float), stream);
    return;
  }
  u16* xb = (u16*)d_ws;
  u16* wqkv = xb + xE;
  u16* qb = wqkv + wE;            // k at qb + 8388608 (EPI0 hardcodes the offset)
  u16* vt = qb + 2 * qE;
  u16* Pm = vt + vtE;
  float* invL = (float*)(Pm + PmE);

  // 1) fp32 -> bf16
  cvt_f32_bf16<<<2048, 256, 0, stream>>>(x, xb, MQKV * E_ / 4);
  cvt_w3<<<3 * E_ * E_ / 4 / 256, 256, 0, stream>>>(Wq, Wk, Wv, wqkv);

  // 2) qk-projection: [8192,1024] x [2048,1024]^T -> q | k (separate, ld 1024)
  //    grid 8 x 32 = 256 blocks = 1 full round
  gemm256<256, 0><<<256, 512, 0, stream>>>(
      xb, wqkv, qb, bq, bk, 2048, E_, 1.f,
      0, 0, 0, E_, E_, 1024, 8, 32);

  // 3) v-projection, transposed: vt[b] = Wv x[b]^T  (M=1024, N=2048, z=4)
  gemm256<128, 1><<<256, 512, 0, stream>>>(
      wqkv + 2 * (size_t)E_ * E_, xb, vt, bv, nullptr, 2048, E_, 1.f,
      0, (long)S_ * E_, (long)1024 * LDP, E_, E_, LDP, 16, 4);

  // 4) expS = exp(q k^T / 32): contiguous q/k reads, LDP-strided Pm writes
  gemm256<256, 2><<<256, 512, 0, stream>>>(
      qb, qb + 8388608, Pm, nullptr, nullptr, 2048, E_, 0.03125f,
      (long)S_ * 1024, (long)S_ * 1024, (long)2048 * LDP, 1024, 1024, LDP, 8, 8);

  // 5) row inverse sums
  row_invsum<<<B_ * S_ / 4, 256, 0, stream>>>(Pm, invL);

  // 6) out = (expS @ V) * invL  (A, B both LDP-strided; out natural ld 1024)
  gemm256<128, 3><<<256, 512, 0, stream>>>(
      Pm, vt, out, invL, nullptr, E_, S_, 1.f,
      (long)2048 * LDP, (long)1024 * LDP, (long)S_ * E_, LDP, LDP, 1024, 8, 8);
}